// Round 10
// baseline (23.241 us; speedup 1.0000x reference)
//
#include <hip/hip_runtime.h>
#include <math.h>

// RulesLoss: B=1024, T=8192  (two kernels; atomics/fence fusion proven bad on
// gfx950 in R5/R6). R10: 1024 blocks x 4 chunks (R9 covered only half the
// domain — 1024x2 chunks != 4096 chunks). Exactly-resident grid (4 blocks/CU),
// 2-deep chunk pipeline with macro-named regs (static indexing, no scratch).
//   gap1 = max(d - e1[tok], 0)               (e1 = +INF for non-IV tokens)
//   gap2 = (tok in RATIO) ? max(fma(dn,-1/3,d), 0) : 0    (dn=+INF at row end)
//   g = gap1 + gap2 ; rules[i] = d[i] - g[i] + g[i+1]
//   out = 0.6 * mean( (log((rules+1)/(d+1)))^2 )

constexpr int TT = 8192;
constexpr int BB = 1024;
constexpr int NBLK = 1024;          // 4 chunks/block; 4096 chunks of 2048 elems
constexpr float LOSS_SCALE = 0.6f;

#define DECL_CHUNK(i) float4 DA##i, DB##i; int4 TA##i, TB##i; \
    float hda##i, hdb##i; int hta##i; bool re##i;

#define LOAD_CHUNK(i, cidx) { \
    int c_ = (cidx); int row_ = c_ >> 2, q_ = c_ & 3; \
    const float* dr_ = dur + (size_t)row_ * TT; \
    const int*   tr_ = tok + (size_t)row_ * TT; \
    int i0_ = q_ * 2048 + tid * 8; \
    DA##i = *reinterpret_cast<const float4*>(dr_ + i0_); \
    DB##i = *reinterpret_cast<const float4*>(dr_ + i0_ + 4); \
    TA##i = *reinterpret_cast<const int4*>(tr_ + i0_); \
    TB##i = *reinterpret_cast<const int4*>(tr_ + i0_ + 4); \
    re##i = (q_ == 3) && (tid == 255); \
    hda##i = 0.0f; hdb##i = 0.0f; hta##i = 0; \
    if (lane == 63 && !re##i) { \
        float2 hh_ = *reinterpret_cast<const float2*>(dr_ + i0_ + 8); \
        hda##i = hh_.x; hdb##i = hh_.y; \
        hta##i = tr_[i0_ + 8]; \
    } \
}

#define COMPUTE_CHUNK(i) { \
    float d[9]; \
    d[0]=DA##i.x; d[1]=DA##i.y; d[2]=DA##i.z; d[3]=DA##i.w; \
    d[4]=DB##i.x; d[5]=DB##i.y; d[6]=DB##i.z; d[7]=DB##i.w; \
    int tk[8] = {TA##i.x, TA##i.y, TA##i.z, TA##i.w, \
                 TB##i.x, TB##i.y, TB##i.z, TB##i.w}; \
    float d8s_ = __shfl_down(d[0], 1, 64); \
    d[8] = (lane == 63) ? (re##i ? INFINITY : hda##i) : d8s_; \
    float g[9]; \
    _Pragma("unroll") \
    for (int j = 0; j < 8; ++j) { \
        float v_ = lut[tk[j] & 127]; \
        float gap1_ = fmaxf(d[j] - fabsf(v_), 0.0f); \
        float gap2_ = (v_ < 0.0f) \
                    ? fmaxf(fmaf(d[j+1], -(1.0f/3.0f), d[j]), 0.0f) : 0.0f; \
        g[j] = gap1_ + gap2_; \
    } \
    float g8s_ = __shfl_down(g[0], 1, 64); \
    if (lane == 63) { \
        float hv_ = lut[hta##i & 127]; \
        float gap1_ = fmaxf(hda##i - fabsf(hv_), 0.0f); \
        float gap2_ = (hv_ < 0.0f) \
                    ? fmaxf(fmaf(hdb##i, -(1.0f/3.0f), hda##i), 0.0f) : 0.0f; \
        g8s_ = re##i ? 0.0f : (gap1_ + gap2_); \
    } \
    g[8] = g8s_; \
    _Pragma("unroll") \
    for (int j = 0; j < 8; ++j) { \
        float dp1_ = d[j] + 1.0f; \
        float num_ = d[j] - g[j] + g[j + 1] + 1.0f; \
        float c_ = __logf(__fdividef(num_, dp1_)); \
        acc = fmaf(c_, c_, acc); \
    } \
}

__global__ __launch_bounds__(256) void rules_partial(const float* __restrict__ dur,
                                                     const int* __restrict__ tok,
                                                     float* __restrict__ partial) {
    int tid = (int)threadIdx.x;
    int lane = tid & 63;
    int bid = (int)blockIdx.x;

    __shared__ float lut[128];

    DECL_CHUNK(0) DECL_CHUNK(1) DECL_CHUNK(2) DECL_CHUNK(3)

    // pipeline: L0 L1 | lut+sync | C0 L2 C1 L3 C2 C3
    LOAD_CHUNK(0, bid)
    LOAD_CHUNK(1, bid + 1024)

    if (tid < 128) {
        int t = tid;
        float e1 = INFINITY;
        if (t == 94 || t == 100 || t == 92) e1 = 2.0f;
        else if (t == 122)                  e1 = 3.0f;
        else if (t == 43 || t == 27)        e1 = 5.0f;
        bool m2 = (t == 44 || t == 28 || t == 29 || t == 27 || t == 121 || t == 43);
        lut[t] = m2 ? -e1 : e1;
    }
    __syncthreads();

    float acc = 0.0f;
    COMPUTE_CHUNK(0)
    LOAD_CHUNK(2, bid + 2048)
    COMPUTE_CHUNK(1)
    LOAD_CHUNK(3, bid + 3072)
    COMPUTE_CHUNK(2)
    COMPUTE_CHUNK(3)

    // wave + block reduce, plain store (no atomics)
#pragma unroll
    for (int off = 32; off; off >>= 1) acc += __shfl_down(acc, off, 64);
    __shared__ float sred[4];
    int wid = tid >> 6;
    if (lane == 0) sred[wid] = acc;
    __syncthreads();
    if (tid == 0) partial[bid] = sred[0] + sred[1] + sred[2] + sred[3];
}

__global__ __launch_bounds__(1024) void rules_final(const float* __restrict__ partial,
                                                    float* __restrict__ out) {
    float acc = partial[threadIdx.x];                    // NBLK == 1024
#pragma unroll
    for (int off = 32; off; off >>= 1) acc += __shfl_down(acc, off, 64);
    __shared__ float sred[16];
    int lane = threadIdx.x & 63, wid = threadIdx.x >> 6;
    if (lane == 0) sred[wid] = acc;
    __syncthreads();
    if (threadIdx.x == 0) {
        float total = 0.0f;
#pragma unroll
        for (int w = 0; w < 16; ++w) total += sred[w];
        out[0] = LOSS_SCALE * (total / (float)((long long)BB * TT));
    }
}

extern "C" void kernel_launch(void* const* d_in, const int* in_sizes, int n_in,
                              void* d_out, int out_size, void* d_ws, size_t ws_size,
                              hipStream_t stream) {
    const float* dur = (const float*)d_in[0];
    const int*   tok = (const int*)d_in[1];
    float* partial = (float*)d_ws;          // 1024 floats, fully rewritten each call
    float* out = (float*)d_out;

    rules_partial<<<NBLK, 256, 0, stream>>>(dur, tok, partial);
    rules_final<<<1, 1024, 0, stream>>>(partial, out);
}